// Round 1
// baseline (217.210 us; speedup 1.0000x reference)
//
#include <hip/hip_runtime.h>

// Adaptive average pooling (16, 512, 512, 64) f32 -> (16, 7, 7, 64) f32.
// Separable: reduce W into ws-scratch [B, H, 7, C], then reduce H.
// All windows for 512->7 are 74 wide; code computes windows generically:
//   start(o) = (o*IN)/OUT, stop(o) = ((o+1)*IN + OUT-1)/OUT   (exact int math)

#define IN_HW  512
#define OUT_HW 7
#define NB     16
#define NC     64
#define C4     16   // float4 groups per spatial position (64 ch / 4)

__device__ __forceinline__ int win_start(int o) { return (o * IN_HW) / OUT_HW; }
__device__ __forceinline__ int win_stop(int o)  { return ((o + 1) * IN_HW + OUT_HW - 1) / OUT_HW; }

// ---------------- pass 1: reduce W ----------------
// grid.x = B*H (8192), block = 128 (112 active: 7 ow * 16 c4)
__global__ __launch_bounds__(128)
void pool_w_kernel(const float4* __restrict__ x, float4* __restrict__ y1) {
    const int tid = threadIdx.x;
    if (tid >= OUT_HW * C4) return;
    const int c4 = tid & 15;
    const int ow = tid >> 4;
    const int bh = blockIdx.x;               // b*512 + h

    const int ws = win_start(ow);
    const int we = win_stop(ow);

    const float4* row = x + (size_t)bh * (IN_HW * C4);

    float4 acc = make_float4(0.f, 0.f, 0.f, 0.f);
    #pragma unroll 4
    for (int w = ws; w < we; ++w) {
        float4 v = row[w * C4 + c4];
        acc.x += v.x; acc.y += v.y; acc.z += v.z; acc.w += v.w;
    }
    y1[((size_t)bh * OUT_HW + ow) * C4 + c4] = acc;
}

// ---------------- pass 2: reduce H + scale ----------------
// total threads = B*7*7*16 = 12544
__global__ __launch_bounds__(256)
void pool_h_kernel(const float4* __restrict__ y1, float4* __restrict__ out) {
    const int idx = blockIdx.x * 256 + threadIdx.x;
    const int total = NB * OUT_HW * OUT_HW * C4;
    if (idx >= total) return;

    const int c4 = idx & 15;
    const int t  = idx >> 4;                 // (b*7 + oh)*7 + ow
    const int ow = t % OUT_HW;
    const int oh = (t / OUT_HW) % OUT_HW;
    const int b  = t / (OUT_HW * OUT_HW);

    const int hs = win_start(oh);
    const int he = win_stop(oh);
    const int wsz = win_stop(ow) - win_start(ow);
    const float scale = 1.0f / (float)((he - hs) * wsz);

    float4 acc = make_float4(0.f, 0.f, 0.f, 0.f);
    #pragma unroll 4
    for (int h = hs; h < he; ++h) {
        float4 v = y1[(((size_t)b * IN_HW + h) * OUT_HW + ow) * C4 + c4];
        acc.x += v.x; acc.y += v.y; acc.z += v.z; acc.w += v.w;
    }
    acc.x *= scale; acc.y *= scale; acc.z *= scale; acc.w *= scale;
    out[idx] = acc;
}

// ---------------- fallback: fused single kernel (if ws too small) ----------------
// grid.x = B*7*7 (784), block = 256; thread = (rowgroup rg 0..15, c4 0..15)
__global__ __launch_bounds__(256)
void pool_fused_kernel(const float4* __restrict__ x, float4* __restrict__ out) {
    __shared__ float4 red[256];

    const int blk = blockIdx.x;              // b*49 + oh*7 + ow
    const int ow = blk % OUT_HW;
    const int oh = (blk / OUT_HW) % OUT_HW;
    const int b  = blk / (OUT_HW * OUT_HW);

    const int tid = threadIdx.x;
    const int c4 = tid & 15;
    const int rg = tid >> 4;                 // 0..15

    const int hs = win_start(oh), he = win_stop(oh);
    const int ws = win_start(ow), we = win_stop(ow);

    float4 acc = make_float4(0.f, 0.f, 0.f, 0.f);
    for (int h = hs + rg; h < he; h += 16) {
        const float4* row = x + ((size_t)(b * IN_HW + h)) * (IN_HW * C4);
        #pragma unroll 4
        for (int w = ws; w < we; ++w) {
            float4 v = row[w * C4 + c4];
            acc.x += v.x; acc.y += v.y; acc.z += v.z; acc.w += v.w;
        }
    }
    red[tid] = acc;
    __syncthreads();

    // tree-reduce over rg (16 groups)
    #pragma unroll
    for (int s = 8; s >= 1; s >>= 1) {
        if (rg < s) {
            float4 o = red[(rg + s) * 16 + c4];
            float4 m = red[rg * 16 + c4];
            m.x += o.x; m.y += o.y; m.z += o.z; m.w += o.w;
            red[rg * 16 + c4] = m;
        }
        __syncthreads();
    }

    if (rg == 0) {
        const float scale = 1.0f / (float)((he - hs) * (we - ws));
        float4 m = red[c4];
        m.x *= scale; m.y *= scale; m.z *= scale; m.w *= scale;
        out[(size_t)blk * C4 + c4] = m;
    }
}

extern "C" void kernel_launch(void* const* d_in, const int* in_sizes, int n_in,
                              void* d_out, int out_size, void* d_ws, size_t ws_size,
                              hipStream_t stream) {
    const float4* x = (const float4*)d_in[0];
    float4* out = (float4*)d_out;

    const size_t ws_needed = (size_t)NB * IN_HW * OUT_HW * NC * sizeof(float);

    if (ws_size >= ws_needed) {
        float4* y1 = (float4*)d_ws;
        pool_w_kernel<<<NB * IN_HW, 128, 0, stream>>>(x, y1);
        const int total = NB * OUT_HW * OUT_HW * C4;
        pool_h_kernel<<<(total + 255) / 256, 256, 0, stream>>>(y1, out);
    } else {
        pool_fused_kernel<<<NB * OUT_HW * OUT_HW, 256, 0, stream>>>(x, out);
    }
}

// Round 2
// 205.848 us; speedup vs baseline: 1.0552x; 1.0552x over previous
//
#include <hip/hip_runtime.h>

// Adaptive average pooling (16, 512, 512, 64) f32 -> (16, 7, 7, 64) f32.
// Separable: reduce W into ws-scratch y1[B][OW][H][C] (transposed so pass 2
// is wave-contiguous), then reduce H with one block per output pixel.
// Windows: start(o) = (o*IN)/OUT, stop(o) = ((o+1)*IN + OUT-1)/OUT.

#define IN_HW  512
#define OUT_HW 7
#define NB     16
#define NC     64
#define C4     16   // float4 groups per spatial position (64 ch / 4)

__device__ __forceinline__ int win_start(int o) { return (o * IN_HW) / OUT_HW; }
__device__ __forceinline__ int win_stop(int o)  { return ((o + 1) * IN_HW + OUT_HW - 1) / OUT_HW; }

// ---------------- pass 1: reduce W ----------------
// grid.x = B*H (8192), block = 128 (112 active: 7 ow * 16 c4)
// writes y1 transposed: y1[((b*7 + ow)*512 + h)*16 + c4]
__global__ __launch_bounds__(128)
void pool_w_kernel(const float4* __restrict__ x, float4* __restrict__ y1) {
    const int tid = threadIdx.x;
    if (tid >= OUT_HW * C4) return;
    const int c4 = tid & 15;
    const int ow = tid >> 4;
    const int bh = blockIdx.x;               // b*512 + h
    const int b  = bh >> 9;
    const int h  = bh & 511;

    const int ws = win_start(ow);
    const int we = win_stop(ow);

    const float4* row = x + (size_t)bh * (IN_HW * C4);

    float4 acc = make_float4(0.f, 0.f, 0.f, 0.f);
    #pragma unroll 8
    for (int w = ws; w < we; ++w) {
        float4 v = row[w * C4 + c4];
        acc.x += v.x; acc.y += v.y; acc.z += v.z; acc.w += v.w;
    }
    y1[(((size_t)b * OUT_HW + ow) * IN_HW + h) * C4 + c4] = acc;
}

// ---------------- pass 2: reduce H + scale ----------------
// grid.x = B*7*7 (784), block = 256: thread = (hc 0..15, c4 0..15)
__global__ __launch_bounds__(256)
void pool_h_kernel(const float4* __restrict__ y1, float4* __restrict__ out) {
    __shared__ float4 red[256];

    const int blk = blockIdx.x;              // (b*7 + oh)*7 + ow
    const int ow = blk % OUT_HW;
    const int oh = (blk / OUT_HW) % OUT_HW;
    const int b  = blk / (OUT_HW * OUT_HW);

    const int tid = threadIdx.x;
    const int c4 = tid & 15;
    const int hc = tid >> 4;                 // 0..15

    const int hs = win_start(oh);
    const int he = win_stop(oh);
    const int wsz = win_stop(ow) - win_start(ow);

    const float4* base = y1 + ((size_t)b * OUT_HW + ow) * (IN_HW * C4);

    float4 acc = make_float4(0.f, 0.f, 0.f, 0.f);
    for (int h = hs + hc; h < he; h += 16) {
        float4 v = base[h * C4 + c4];
        acc.x += v.x; acc.y += v.y; acc.z += v.z; acc.w += v.w;
    }
    red[tid] = acc;
    __syncthreads();

    #pragma unroll
    for (int s = 8; s >= 1; s >>= 1) {
        if (hc < s) {
            float4 o = red[(hc + s) * 16 + c4];
            float4 m = red[hc * 16 + c4];
            m.x += o.x; m.y += o.y; m.z += o.z; m.w += o.w;
            red[hc * 16 + c4] = m;
        }
        __syncthreads();
    }

    if (hc == 0) {
        const float scale = 1.0f / (float)((he - hs) * wsz);
        float4 m = red[c4];
        m.x *= scale; m.y *= scale; m.z *= scale; m.w *= scale;
        out[(size_t)blk * C4 + c4] = m;
    }
}

// ---------------- fallback: fused single kernel (if ws too small) ----------------
__global__ __launch_bounds__(256)
void pool_fused_kernel(const float4* __restrict__ x, float4* __restrict__ out) {
    __shared__ float4 red[256];

    const int blk = blockIdx.x;              // b*49 + oh*7 + ow
    const int ow = blk % OUT_HW;
    const int oh = (blk / OUT_HW) % OUT_HW;
    const int b  = blk / (OUT_HW * OUT_HW);

    const int tid = threadIdx.x;
    const int c4 = tid & 15;
    const int rg = tid >> 4;                 // 0..15

    const int hs = win_start(oh), he = win_stop(oh);
    const int ws = win_start(ow), we = win_stop(ow);

    float4 acc = make_float4(0.f, 0.f, 0.f, 0.f);
    for (int h = hs + rg; h < he; h += 16) {
        const float4* row = x + ((size_t)(b * IN_HW + h)) * (IN_HW * C4);
        #pragma unroll 8
        for (int w = ws; w < we; ++w) {
            float4 v = row[w * C4 + c4];
            acc.x += v.x; acc.y += v.y; acc.z += v.z; acc.w += v.w;
        }
    }
    red[tid] = acc;
    __syncthreads();

    #pragma unroll
    for (int s = 8; s >= 1; s >>= 1) {
        if (rg < s) {
            float4 o = red[(rg + s) * 16 + c4];
            float4 m = red[rg * 16 + c4];
            m.x += o.x; m.y += o.y; m.z += o.z; m.w += o.w;
            red[rg * 16 + c4] = m;
        }
        __syncthreads();
    }

    if (rg == 0) {
        const float scale = 1.0f / (float)((he - hs) * (we - ws));
        float4 m = red[c4];
        m.x *= scale; m.y *= scale; m.z *= scale; m.w *= scale;
        out[(size_t)blk * C4 + c4] = m;
    }
}

extern "C" void kernel_launch(void* const* d_in, const int* in_sizes, int n_in,
                              void* d_out, int out_size, void* d_ws, size_t ws_size,
                              hipStream_t stream) {
    const float4* x = (const float4*)d_in[0];
    float4* out = (float4*)d_out;

    const size_t ws_needed = (size_t)NB * OUT_HW * IN_HW * NC * sizeof(float);

    if (ws_size >= ws_needed) {
        float4* y1 = (float4*)d_ws;
        pool_w_kernel<<<NB * IN_HW, 128, 0, stream>>>(x, y1);
        pool_h_kernel<<<NB * OUT_HW * OUT_HW, 256, 0, stream>>>(y1, out);
    } else {
        pool_fused_kernel<<<NB * OUT_HW * OUT_HW, 256, 0, stream>>>(x, out);
    }
}